// Round 5
// baseline (487.378 us; speedup 1.0000x reference)
//
#include <hip/hip_runtime.h>
#include <math.h>

// GCN 3-layer forward, N=100000, E=3200000, F=256 -> 8 -> 4 -> 16.
// Round 5: same structure as round 4 (bucketed records, SoA LDS accumulators),
// but all fp32 LDS atomicAdd -> unsafeAtomicAdd (native ds_add_f32). Plain
// atomicAdd(float*) lowers to a CAS retry loop without -munsafe-fp-atomics,
// which serialized the layer kernels (154us with every pipe <3% busy).

#define N_NODES 100000
#define N_EDGES 3200000
#define BN 64                        // nodes per bucket
#define NBUK 1563                    // ceil(N/BN)
#define NCHUNK 256
#define CHUNK_E (N_EDGES / NCHUNK)   // 12500

__device__ __forceinline__ float eluf(float v) { return v > 0.0f ? v : expm1f(v); }

// Native LDS float add (ds_add_f32, no return). atomicAdd(float*) without
// -munsafe-fp-atomics compiles to a CAS loop -- catastrophic under contention.
__device__ __forceinline__ void lds_add(float* p, float v) { unsafeAtomicAdd(p, v); }

__device__ __forceinline__ int ld_edge(const void* __restrict__ raw, int is64, long long idx) {
  return is64 ? (int)((const long long*)raw)[idx] : ((const int*)raw)[idx];
}

// Detect whether edge_index arrived as int64 (odd u32 words of first 64 all 0)
__global__ void detect_kernel(const unsigned int* __restrict__ ei, int* __restrict__ flag) {
  if (blockIdx.x == 0 && threadIdx.x == 0) {
    int is64 = 1;
    for (int i = 0; i < 32; ++i)
      if (ei[2 * i + 1] != 0u) { is64 = 0; break; }
    *flag = is64;
  }
}

// Phase A: per-(chunk,bucket) edge counts via LDS histogram (int atomics: native).
__global__ __launch_bounds__(512) void count_kernel(const void* __restrict__ raw,
                                                    const int* __restrict__ flag,
                                                    int* __restrict__ cnt) {
  __shared__ int c[NBUK];
  const int tid = threadIdx.x;
  for (int i = tid; i < NBUK; i += 512) c[i] = 0;
  __syncthreads();
  const int is64 = *flag;
  const int c0 = blockIdx.x * CHUNK_E;
  for (int e = c0 + tid; e < c0 + CHUNK_E; e += 512) {
    int d = ld_edge(raw, is64, (long long)N_EDGES + e);
    if ((unsigned)d < (unsigned)N_NODES) atomicAdd(&c[d >> 6], 1);
  }
  __syncthreads();
  for (int i = tid; i < NBUK; i += 512) cnt[blockIdx.x * NBUK + i] = c[i];
}

// Column-scan cnt (exclusive per bucket over chunks) + exclusive scan of
// bucket totals -> bucketBase[NBUK+1]. One block, 1024 threads, 2 buckets/thread.
__global__ __launch_bounds__(1024) void scan_kernel(int* __restrict__ cnt,
                                                    int* __restrict__ bucketBase) {
  __shared__ int sdata[1024];
  __shared__ int sTA;
  const int t = threadIdx.x;
  int T0 = 0;
  {
    int run = 0;
    for (int c = 0; c < NCHUNK; ++c) {
      int idx = c * NBUK + t;
      int v = cnt[idx];
      cnt[idx] = run;
      run += v;
    }
    T0 = run;
  }
  const int b1 = 1024 + t;
  int T1 = 0;
  if (b1 < NBUK) {
    int run = 0;
    for (int c = 0; c < NCHUNK; ++c) {
      int idx = c * NBUK + b1;
      int v = cnt[idx];
      cnt[idx] = run;
      run += v;
    }
    T1 = run;
  }
  sdata[t] = T0;
  __syncthreads();
  for (int off = 1; off < 1024; off <<= 1) {
    int v = (t >= off) ? sdata[t - off] : 0;
    __syncthreads();
    sdata[t] += v;
    __syncthreads();
  }
  int incl0 = sdata[t];
  if (t == 1023) sTA = sdata[1023];
  __syncthreads();
  const int TA = sTA;
  sdata[t] = T1;
  __syncthreads();
  for (int off = 1; off < 1024; off <<= 1) {
    int v = (t >= off) ? sdata[t - off] : 0;
    __syncthreads();
    sdata[t] += v;
    __syncthreads();
  }
  int incl1 = sdata[t];
  bucketBase[t] = incl0 - T0;
  if (b1 < NBUK) bucketBase[b1] = TA + incl1 - T1;
  if (b1 == NBUK - 1) bucketBase[NBUK] = TA + incl1;
}

// Phase C: place records {src:17b | local:6b<<17, w} into bucket-grouped order.
__global__ __launch_bounds__(512) void place_kernel(const void* __restrict__ raw,
                                                    const int* __restrict__ flag,
                                                    const float* __restrict__ w,
                                                    const int* __restrict__ cnt,
                                                    const int* __restrict__ bucketBase,
                                                    int2* __restrict__ recs) {
  __shared__ int cur[NBUK];
  const int tid = threadIdx.x;
  for (int i = tid; i < NBUK; i += 512)
    cur[i] = cnt[blockIdx.x * NBUK + i] + bucketBase[i];
  __syncthreads();
  const int is64 = *flag;
  const int c0 = blockIdx.x * CHUNK_E;
  for (int e = c0 + tid; e < c0 + CHUNK_E; e += 512) {
    int s = ld_edge(raw, is64, e);
    int d = ld_edge(raw, is64, (long long)N_EDGES + e);
    if ((unsigned)s >= (unsigned)N_NODES || (unsigned)d >= (unsigned)N_NODES) continue;
    float wv = w[e];
    int bkt = d >> 6, loc = d & 63;
    int pos = atomicAdd(&cur[bkt], 1);
    recs[pos] = make_int2(s | (loc << 17), __float_as_int(wv));
  }
}

// Weighted degree per bucket via native LDS float adds -> dis = rsqrt(deg + 1).
__global__ __launch_bounds__(256) void deg_kernel(const int2* __restrict__ recs,
                                                  const int* __restrict__ bucketBase,
                                                  float* __restrict__ dis) {
  __shared__ float acc[BN];
  const int b = blockIdx.x, tid = threadIdx.x;
  if (tid < BN) acc[tid] = 0.0f;
  __syncthreads();
  const int beg = bucketBase[b], end = bucketBase[b + 1];
  for (int i = beg + tid; i < end; i += 256) {
    int2 r = recs[i];
    lds_add(&acc[(r.x >> 17) & 63], __int_as_float(r.y));
  }
  __syncthreads();
  int n = b * BN + tid;
  if (tid < BN && n < N_NODES) dis[n] = rsqrtf(acc[tid] + 1.0f);
}

// m1s[n] = dis[n] * (x[n] @ W1); one wave per node row (64 lanes x float4).
__global__ __launch_bounds__(256) void transform1_kernel(const float* __restrict__ x,
                                                         const float* __restrict__ W1,
                                                         const float* __restrict__ dis,
                                                         float* __restrict__ m1s) {
  const int lane = threadIdx.x & 63;
  const int gwave = blockIdx.x * 4 + (threadIdx.x >> 6);
  const int nwaves = gridDim.x * 4;
  float wreg[4][8];
#pragma unroll
  for (int i = 0; i < 4; ++i)
#pragma unroll
    for (int j = 0; j < 8; ++j)
      wreg[i][j] = W1[(lane * 4 + i) * 8 + j];
  for (int n = gwave; n < N_NODES; n += nwaves) {
    float4 xv = *(const float4*)(x + (size_t)n * 256 + lane * 4);
    float acc[8];
#pragma unroll
    for (int j = 0; j < 8; ++j)
      acc[j] = xv.x * wreg[0][j] + xv.y * wreg[1][j] + xv.z * wreg[2][j] + xv.w * wreg[3][j];
#pragma unroll
    for (int off = 32; off > 0; off >>= 1)
#pragma unroll
      for (int j = 0; j < 8; ++j)
        acc[j] += __shfl_down(acc[j], off);
    if (lane == 0) {
      float di = dis[n];
      float4* o = (float4*)(m1s + (size_t)n * 8);
      o[0] = make_float4(di * acc[0], di * acc[1], di * acc[2], di * acc[3]);
      o[1] = make_float4(di * acc[4], di * acc[5], di * acc[6], di * acc[7]);
    }
  }
}

// Layer 1: agg = sum w*disL[loc]*m1s[s] + dis[n]*m1s[n]; h=elu(agg+b1);
// m2s[n] = dis[n] * (h @ W2).
__global__ __launch_bounds__(256) void layer1_kernel(const int2* __restrict__ recs,
                                                     const int* __restrict__ bucketBase,
                                                     const float* __restrict__ m1s,
                                                     const float* __restrict__ dis,
                                                     const float* __restrict__ b1,
                                                     const float* __restrict__ W2,
                                                     float* __restrict__ m2s) {
  __shared__ float acc[8][BN];
  __shared__ float disL[BN];
  const int b = blockIdx.x, tid = threadIdx.x;
  if (tid < BN) {
    int n = b * BN + tid;
    disL[tid] = (n < N_NODES) ? dis[n] : 0.0f;
  }
  for (int i = tid; i < 8 * BN; i += 256) ((float*)acc)[i] = 0.0f;
  __syncthreads();
  const int beg = bucketBase[b], end = bucketBase[b + 1];
  for (int i = beg + tid; i < end; i += 256) {
    int2 r = recs[i];
    int s = r.x & 0x1FFFF;
    int loc = (r.x >> 17) & 63;
    float nw = __int_as_float(r.y) * disL[loc];
    const float4* f = (const float4*)(m1s + (size_t)s * 8);
    float4 v0 = f[0], v1 = f[1];
    lds_add(&acc[0][loc], nw * v0.x);
    lds_add(&acc[1][loc], nw * v0.y);
    lds_add(&acc[2][loc], nw * v0.z);
    lds_add(&acc[3][loc], nw * v0.w);
    lds_add(&acc[4][loc], nw * v1.x);
    lds_add(&acc[5][loc], nw * v1.y);
    lds_add(&acc[6][loc], nw * v1.z);
    lds_add(&acc[7][loc], nw * v1.w);
  }
  __syncthreads();
  int n = b * BN + tid;
  if (tid < BN && n < N_NODES) {
    float di = disL[tid];
    const float4* mm = (const float4*)(m1s + (size_t)n * 8);
    float4 s0 = mm[0], s1 = mm[1];
    float h[8];
    h[0] = eluf(acc[0][tid] + di * s0.x + b1[0]);
    h[1] = eluf(acc[1][tid] + di * s0.y + b1[1]);
    h[2] = eluf(acc[2][tid] + di * s0.z + b1[2]);
    h[3] = eluf(acc[3][tid] + di * s0.w + b1[3]);
    h[4] = eluf(acc[4][tid] + di * s1.x + b1[4]);
    h[5] = eluf(acc[5][tid] + di * s1.y + b1[5]);
    h[6] = eluf(acc[6][tid] + di * s1.z + b1[6]);
    h[7] = eluf(acc[7][tid] + di * s1.w + b1[7]);
    float o0 = 0.f, o1 = 0.f, o2 = 0.f, o3 = 0.f;
#pragma unroll
    for (int i = 0; i < 8; ++i) {
      float hi = h[i];
      o0 += hi * W2[i * 4 + 0];
      o1 += hi * W2[i * 4 + 1];
      o2 += hi * W2[i * 4 + 2];
      o3 += hi * W2[i * 4 + 3];
    }
    *(float4*)(m2s + (size_t)n * 4) = make_float4(di * o0, di * o1, di * o2, di * o3);
  }
}

// Layer 2: agg = sum w*disL*m2s[s] + dis[n]*m2s[n]; h2s[n] = dis[n]*elu(agg+b2).
__global__ __launch_bounds__(256) void layer2_kernel(const int2* __restrict__ recs,
                                                     const int* __restrict__ bucketBase,
                                                     const float* __restrict__ m2s,
                                                     const float* __restrict__ dis,
                                                     const float* __restrict__ b2,
                                                     float* __restrict__ h2s) {
  __shared__ float acc[4][BN];
  __shared__ float disL[BN];
  const int b = blockIdx.x, tid = threadIdx.x;
  if (tid < BN) {
    int n = b * BN + tid;
    disL[tid] = (n < N_NODES) ? dis[n] : 0.0f;
  }
  for (int i = tid; i < 4 * BN; i += 256) ((float*)acc)[i] = 0.0f;
  __syncthreads();
  const int beg = bucketBase[b], end = bucketBase[b + 1];
  for (int i = beg + tid; i < end; i += 256) {
    int2 r = recs[i];
    int s = r.x & 0x1FFFF;
    int loc = (r.x >> 17) & 63;
    float nw = __int_as_float(r.y) * disL[loc];
    float4 v = *(const float4*)(m2s + (size_t)s * 4);
    lds_add(&acc[0][loc], nw * v.x);
    lds_add(&acc[1][loc], nw * v.y);
    lds_add(&acc[2][loc], nw * v.z);
    lds_add(&acc[3][loc], nw * v.w);
  }
  __syncthreads();
  int n = b * BN + tid;
  if (tid < BN && n < N_NODES) {
    float di = disL[tid];
    float4 s = *(const float4*)(m2s + (size_t)n * 4);
    float4 r;
    r.x = di * eluf(acc[0][tid] + di * s.x + b2[0]);
    r.y = di * eluf(acc[1][tid] + di * s.y + b2[1]);
    r.z = di * eluf(acc[2][tid] + di * s.z + b2[2]);
    r.w = di * eluf(acc[3][tid] + di * s.w + b2[3]);
    *(float4*)(h2s + (size_t)n * 4) = r;
  }
}

// Layer 3: agg = sum w*disL*h2s[s] + dis[n]*h2s[n]; out = agg @ W3 + b3.
__global__ __launch_bounds__(256) void layer3_kernel(const int2* __restrict__ recs,
                                                     const int* __restrict__ bucketBase,
                                                     const float* __restrict__ h2s,
                                                     const float* __restrict__ dis,
                                                     const float* __restrict__ b3,
                                                     const float* __restrict__ W3,
                                                     float* __restrict__ out) {
  __shared__ float acc[4][BN];
  __shared__ float disL[BN];
  const int b = blockIdx.x, tid = threadIdx.x;
  if (tid < BN) {
    int n = b * BN + tid;
    disL[tid] = (n < N_NODES) ? dis[n] : 0.0f;
  }
  for (int i = tid; i < 4 * BN; i += 256) ((float*)acc)[i] = 0.0f;
  __syncthreads();
  const int beg = bucketBase[b], end = bucketBase[b + 1];
  for (int i = beg + tid; i < end; i += 256) {
    int2 r = recs[i];
    int s = r.x & 0x1FFFF;
    int loc = (r.x >> 17) & 63;
    float nw = __int_as_float(r.y) * disL[loc];
    float4 v = *(const float4*)(h2s + (size_t)s * 4);
    lds_add(&acc[0][loc], nw * v.x);
    lds_add(&acc[1][loc], nw * v.y);
    lds_add(&acc[2][loc], nw * v.z);
    lds_add(&acc[3][loc], nw * v.w);
  }
  __syncthreads();
  int n = b * BN + tid;
  if (tid < BN && n < N_NODES) {
    float di = disL[tid];
    float4 s = *(const float4*)(h2s + (size_t)n * 4);
    float g0 = acc[0][tid] + di * s.x;
    float g1 = acc[1][tid] + di * s.y;
    float g2 = acc[2][tid] + di * s.z;
    float g3 = acc[3][tid] + di * s.w;
    float o[16];
#pragma unroll
    for (int c = 0; c < 16; ++c)
      o[c] = b3[c] + g0 * W3[c] + g1 * W3[16 + c] + g2 * W3[32 + c] + g3 * W3[48 + c];
    float4* op = (float4*)(out + (size_t)n * 16);
    op[0] = make_float4(o[0], o[1], o[2], o[3]);
    op[1] = make_float4(o[4], o[5], o[6], o[7]);
    op[2] = make_float4(o[8], o[9], o[10], o[11]);
    op[3] = make_float4(o[12], o[13], o[14], o[15]);
  }
}

extern "C" void kernel_launch(void* const* d_in, const int* in_sizes, int n_in,
                              void* d_out, int out_size, void* d_ws, size_t ws_size,
                              hipStream_t stream) {
  const float* x = (const float*)d_in[0];
  const void* ei = d_in[1];
  const float* w = (const float*)d_in[2];
  const float* W1 = (const float*)d_in[3];
  const float* b1 = (const float*)d_in[4];
  const float* W2 = (const float*)d_in[5];
  const float* b2 = (const float*)d_in[6];
  const float* W3 = (const float*)d_in[7];
  const float* b3 = (const float*)d_in[8];
  float* out = (float*)d_out;
  float* ws = (float*)d_ws;

  // ws layout (4-byte words); recs first (8B-aligned at 0).
  int2* recs = (int2*)ws;                         // [E] int2      (6,400,000 w)
  float* m1s = ws + 6400000;                      // [8N]          (800,000 w)
  float* m2s = ws + 7200000;                      // [4N]          (400,000 w)
  float* h2s = ws + 7600000;                      // [4N]          (400,000 w)
  int* cnt = (int*)(ws + 8000000);                // [NCHUNK*NBUK] (400,128 w)
  int* bucketBase = (int*)(ws + 8400128);         // [NBUK+1]      (1,564 w)
  float* dis = ws + 8401692;                      // [N]           (100,000 w)
  int* flag = (int*)(ws + 8501692);               // [1]
  // total ~= 8,501,693 words ~= 34 MB

  detect_kernel<<<1, 64, 0, stream>>>((const unsigned int*)ei, flag);
  count_kernel<<<NCHUNK, 512, 0, stream>>>(ei, flag, cnt);
  scan_kernel<<<1, 1024, 0, stream>>>(cnt, bucketBase);
  place_kernel<<<NCHUNK, 512, 0, stream>>>(ei, flag, w, cnt, bucketBase, recs);
  deg_kernel<<<NBUK, 256, 0, stream>>>(recs, bucketBase, dis);
  transform1_kernel<<<4096, 256, 0, stream>>>(x, W1, dis, m1s);
  layer1_kernel<<<NBUK, 256, 0, stream>>>(recs, bucketBase, m1s, dis, b1, W2, m2s);
  layer2_kernel<<<NBUK, 256, 0, stream>>>(recs, bucketBase, m2s, dis, b2, h2s);
  layer3_kernel<<<NBUK, 256, 0, stream>>>(recs, bucketBase, h2s, dis, b3, W3, out);
}